// Round 9
// baseline (780.749 us; speedup 1.0000x reference)
//
#include <hip/hip_runtime.h>
#include <hip/hip_cooperative_groups.h>

namespace cg = cooperative_groups;

typedef __attribute__((ext_vector_type(8))) __bf16 bf16x8;
typedef __attribute__((ext_vector_type(4))) float f32x4;
typedef _Float16 hf2 __attribute__((ext_vector_type(2)));
typedef _Float16 hf8 __attribute__((ext_vector_type(8)));
typedef unsigned short u16;
typedef struct { hf2 v[4]; } hf2x4;   // register-friendly view of hf8

__device__ __forceinline__ float bf2f(u16 h) {
    return __uint_as_float(((unsigned int)h) << 16);
}
__device__ __forceinline__ u16 f2bf(float f) {
    unsigned int u = __float_as_uint(f);
    u += 0x7fffu + ((u >> 16) & 1u);   // RNE
    return (u16)(u >> 16);
}

#if __has_builtin(__builtin_amdgcn_fdot2)
__device__ __forceinline__ float FDOT2(hf2 a, hf2 b, float c) {
    return __builtin_amdgcn_fdot2(a, b, c, false);
}
#else
__device__ __forceinline__ float FDOT2(hf2 a, hf2 b, float c) {
    return c + (float)a[0] + (float)a[1];   // b is all-ones in our use
}
#endif

#define GLOAD_LDS16(gsrc, ldst)                                                          \
    __builtin_amdgcn_global_load_lds(                                                    \
        (__attribute__((address_space(1))) unsigned int*)(gsrc),                         \
        (__attribute__((address_space(3))) unsigned int*)(ldst), 16, 0, 0)

struct CvtDesc { const float* src; u16* dst; int N, K, Npad, Kpad, blk0, fmt; };
struct CvtTab { CvtDesc t[11]; };

struct MegaArgs {
    CvtTab tab; int cvt_blocks;
    const u16 *xb, *aWb, *Wd0b, *Wd1b, *Wd2b, *Wd3b, *Wu0b, *Wu1b, *Wu2b, *Wu3b;
    const float *ab, *bd0, *bd1, *bd2, *bd3, *bu0, *bu1, *bu2, *bu3;
    u16 *h1, *u2;
    _Float16 *adFH, *featH;
    const _Float16 *proH;
    float *part, *out;
};

// ---------------------------------------------------------------------------
// 128x64-tile double-buffered bf16 MFMA GEMM (2-phase pipeline): STAGE(next)
// issued BEFORE COMPUTE(cur); one vmcnt-drain barrier per K-step.
// 256 thr = 4 waves as 2x2 over (128,64); wave tile 64x32 = acc[4][2].
// XOR-swizzled granules via pre-swizzled global source + linear LDS dest.
// ---------------------------------------------------------------------------
template<int RELU, int HASRES, int RESF16, int MODE>
__device__ __forceinline__ void gemm128_body(
    char* lds,
    const u16* __restrict__ A, int lda,
    const u16* __restrict__ W, int ldw,
    const float* __restrict__ bias,
    u16* __restrict__ outB, int ldo,
    const void* __restrict__ res, int ldr,
    _Float16* __restrict__ outH,
    int nk, int mb, int nb)
{
    const int tid = threadIdx.x;
    const int wave = tid >> 6, lane = tid & 63;
    const int lr = lane & 15, lk = lane >> 4;
    const int wr = wave >> 1, wc = wave & 1;

    f32x4 acc[4][2];
#pragma unroll
    for (int i = 0; i < 4; ++i)
#pragma unroll
        for (int j = 0; j < 2; ++j)
#pragma unroll
            for (int e = 0; e < 4; ++e) acc[i][j][e] = 0.f;

    int ra[4], la[4], rb_[2], lb[2];
#pragma unroll
    for (int t = 0; t < 4; ++t) {
        int g = t * 256 + tid;
        ra[t] = g >> 3; la[t] = (g & 7) ^ (ra[t] & 7);
    }
#pragma unroll
    for (int t = 0; t < 2; ++t) {
        int g = t * 256 + tid;
        rb_[t] = g >> 3; lb[t] = (g & 7) ^ (rb_[t] & 7);
    }

    auto STAGE = [&](int b, int kt) {
        const int kk = kt * 64;
        char* dA = lds + b * 24576;
        char* dB = dA + 16384;
#pragma unroll
        for (int t = 0; t < 4; ++t)
            GLOAD_LDS16(A + (size_t)(mb + ra[t]) * lda + kk + la[t] * 8,
                        dA + t * 4096 + wave * 1024);
#pragma unroll
        for (int t = 0; t < 2; ++t)
            GLOAD_LDS16(W + (size_t)(nb + rb_[t]) * ldw + kk + lb[t] * 8,
                        dB + t * 4096 + wave * 1024);
    };
    auto COMPUTE = [&](int b) {
        char* sA = lds + b * 24576;
        char* sB = sA + 16384;
#pragma unroll
        for (int ks = 0; ks < 2; ++ks) {
            bf16x8 af[4], bfr[2];
#pragma unroll
            for (int mi = 0; mi < 4; ++mi) {
                int m_loc = wr * 64 + mi * 16 + lr;
                int gr = (ks * 4 + lk) ^ (m_loc & 7);
                af[mi] = *(const bf16x8*)(sA + m_loc * 128 + gr * 16);
            }
#pragma unroll
            for (int ni = 0; ni < 2; ++ni) {
                int n_loc = wc * 32 + ni * 16 + lr;
                int gr = (ks * 4 + lk) ^ (n_loc & 7);
                bfr[ni] = *(const bf16x8*)(sB + n_loc * 128 + gr * 16);
            }
#pragma unroll
            for (int mi = 0; mi < 4; ++mi)
#pragma unroll
                for (int ni = 0; ni < 2; ++ni)
                    acc[mi][ni] = __builtin_amdgcn_mfma_f32_16x16x32_bf16(
                        af[mi], bfr[ni], acc[mi][ni], 0, 0, 0);
        }
    };

    STAGE(0, 0);
    __syncthreads();
    int b = 0;
    for (int kt = 0; kt < nk - 1; ++kt) {
        STAGE(b ^ 1, kt + 1);
        COMPUTE(b);
        __syncthreads();
        b ^= 1;
    }
    COMPUTE(b);

#pragma unroll
    for (int mi = 0; mi < 4; ++mi) {
#pragma unroll
        for (int ni = 0; ni < 2; ++ni) {
            const int n_g = nb + wc * 32 + ni * 16 + lr;
            const float bv = bias[n_g];
#pragma unroll
            for (int r = 0; r < 4; ++r) {
                const int m_g = mb + wr * 64 + mi * 16 + lk * 4 + r;
                float v = acc[mi][ni][r] + bv;
                if (RELU) v = fmaxf(v, 0.f);
                if (HASRES) {
                    if (RESF16)
                        v += (float)((const _Float16*)res)[(size_t)m_g * ldr + n_g];
                    else
                        v += bf2f(((const u16*)res)[(size_t)m_g * ldr + n_g]);
                }
                if (MODE == 2) outH[(size_t)m_g * 768 + n_g] = (_Float16)v;
                else           outB[(size_t)m_g * ldo + n_g] = f2bf(v);
            }
        }
    }
}

// small per-16-row layer: weights direct from global (L2-resident)
template<int K, int NPAD, int NREAL, int RES, int OUTG>
__device__ __forceinline__ void layer16(
    const u16* __restrict__ W, int ldw, const float* __restrict__ bias,
    const u16* actIn, int ldin,
    u16* actOut, int ldout,
    const u16* resid, int ldres,
    u16* __restrict__ gout, int ldg)
{
    constexpr int TPW = NPAD / 64;
    const int tid = threadIdx.x;
    const int wave = tid >> 6, lane = tid & 63;
    const int lr = lane & 15, lk = lane >> 4;

    f32x4 acc[TPW];
#pragma unroll
    for (int t = 0; t < TPW; ++t)
#pragma unroll
        for (int e = 0; e < 4; ++e) acc[t][e] = 0.f;

#pragma unroll
    for (int kk = 0; kk < K / 32; ++kk) {
        const bf16x8 a = *(const bf16x8*)&actIn[lr * ldin + kk * 32 + lk * 8];
#pragma unroll
        for (int t = 0; t < TPW; ++t) {
            const int nc = (wave * TPW + t) * 16 + lr;
            const bf16x8 b = *(const bf16x8*)&W[(size_t)nc * ldw + kk * 32 + lk * 8];
            acc[t] = __builtin_amdgcn_mfma_f32_16x16x32_bf16(a, b, acc[t], 0, 0, 0);
        }
    }
#pragma unroll
    for (int t = 0; t < TPW; ++t) {
        const int nc = (wave * TPW + t) * 16 + lr;
        const float bv = (nc < NREAL) ? bias[nc] : 0.f;
#pragma unroll
        for (int r = 0; r < 4; ++r) {
            const int row = lk * 4 + r;
            float v = fmaxf(acc[t][r] + bv, 0.f);
            if (RES) v += bf2f(resid[row * ldres + nc]);
            const u16 o = f2bf(v);
            if (OUTG) gout[(size_t)row * ldg + nc] = o;
            else      actOut[row * ldout + nc] = o;
        }
    }
}

// ---------------------------------------------------------------------------
// Cooperative mega-kernel: cvt -> ad0 -> chain -> u3 -> l1 -> reduce,
// separated by grid.sync(). 512 blocks x 256 thr (2 blocks/CU co-resident;
// LDS 48KB, __launch_bounds__(256,2) caps VGPR for 2 blocks/CU).
// ---------------------------------------------------------------------------
__global__ __launch_bounds__(256, 2) void mega(MegaArgs a) {
    __shared__ __align__(16) char smem[49152];
    cg::grid_group grid = cg::this_grid();
    const int bid = blockIdx.x;
    const int tid = threadIdx.x;

    // ---- phase 0: convert/pad (grid-stride over virtual cvt blocks) ----
    for (int vb = bid; vb < a.cvt_blocks; vb += 512) {
        int ti = 0;
#pragma unroll
        for (int j = 1; j < 11; ++j)
            if (vb >= a.tab.t[j].blk0) ti = j;
        const CvtDesc c = a.tab.t[ti];
        long i = (long)(vb - c.blk0) * 256 + tid;
        long tot = (long)c.Npad * c.Kpad;
        if (i < tot) {
            int n = (int)(i / c.Kpad);
            int k = (int)(i - (long)n * c.Kpad);
            float v = (n < c.N && k < c.K) ? c.src[(long)n * c.K + k] : 0.f;
            c.dst[i] = c.fmt ? __builtin_bit_cast(u16, (_Float16)v) : f2bf(v);
        }
    }
    __threadfence();
    grid.sync();
    __threadfence();

    // ---- phase 1: adapter (adFH = f16(x@aW.T+ab+xb)) + down0 (h1) ----
    if (bid < 288) {
        const int tx = bid & 15, ty = bid >> 4;
        if (ty < 12)
            gemm128_body<0, 1, 0, 2>(smem, a.xb, 768, a.aWb, 768, a.ab,
                                     nullptr, 0, a.xb, 768, a.adFH, 12,
                                     tx * 128, ty * 64);
        else
            gemm128_body<1, 0, 0, 0>(smem, a.xb, 768, a.Wd0b, 768, a.bd0,
                                     a.h1, 384, nullptr, 0, nullptr, 12,
                                     tx * 128, (ty - 12) * 64);
    }
    __threadfence();
    grid.sync();
    __threadfence();

    // ---- phase 2: chain d1..u2 (16 rows/block, 128 blocks) ----
    if (bid < 128) {
        u16* As = (u16*)smem;               // 16x392
        u16* Bs = (u16*)(smem + 12544);     // 16x200
        u16* Cs = (u16*)(smem + 18944);     // 16x136
        u16* Ds = (u16*)(smem + 23296);     // 16x72
        const int rb = bid * 16;
        for (int i = tid; i < 768; i += 256) {
            const int r = i / 48, c = i - r * 48;
            *(bf16x8*)&As[r * 392 + c * 8] =
                *(const bf16x8*)&a.h1[(size_t)(rb + r) * 384 + c * 8];
        }
        __syncthreads();
        layer16<384, 192, 192, 0, 0>(a.Wd1b, 384, a.bd1, As, 392, Bs, 200, nullptr, 0, nullptr, 0);
        __syncthreads();
        layer16<192, 128,  96, 0, 0>(a.Wd2b, 192, a.bd2, Bs, 200, Cs, 136, nullptr, 0, nullptr, 0);
        __syncthreads();
        layer16<128,  64,  48, 0, 0>(a.Wd3b, 128, a.bd3, Cs, 136, Ds,  72, nullptr, 0, nullptr, 0);
        __syncthreads();
        u16* E = As;                 // 16 x 136
        u16* F = As + 16 * 136;      // 16 x 200
        layer16< 64, 128,  96, 1, 0>(a.Wu0b,  64, a.bu0, Ds,  72, E, 136, Cs, 136, nullptr, 0);
        __syncthreads();
        layer16<128, 192, 192, 1, 0>(a.Wu1b, 128, a.bu1, E, 136, F, 200, Bs, 200, nullptr, 0);
        __syncthreads();
        layer16<192, 384, 384, 0, 1>(a.Wu2b, 192, a.bu2, F, 200, nullptr, 0, nullptr, 0,
                                     a.u2 + (size_t)rb * 384, 384);
    }
    __threadfence();
    grid.sync();
    __threadfence();

    // ---- phase 3: u3 (featH = f16(relu(u2@Wu3.T+bu3) + adFH)) ----
    if (bid < 192) {
        const int tx = bid & 15, ty = bid >> 4;
        gemm128_body<1, 1, 1, 2>(smem, a.u2, 384, a.Wu3b, 384, a.bu3,
                                 nullptr, 0, a.adFH, 768, a.featH, 6,
                                 tx * 128, ty * 64);
    }
    __threadfence();
    grid.sync();
    __threadfence();

    // ---- phase 4: l1 partials (128 rows x 64 protos x 96 d per block) ----
    {
        auto fs = (_Float16(*)[96])smem;            // 24576 B
        auto pt = (hf2(*)[64])(smem + 24576);       // 12288 B
        const int rbk = bid & 15, pbk = (bid >> 4) & 3, z = bid >> 6;
        const int rb = rbk * 128, pb = pbk * 64, db = z * 96;
        const int tp = tid & 15, tr = tid >> 4;

        __syncthreads();   // smem reuse guard (phase 3 done for this block)
        for (int i = tid; i < 1536; i += 256) {
            const int r = i / 12, c = i - r * 12;
            *(hf8*)&fs[r][c * 8] =
                *(const hf8*)&a.featH[(size_t)(rb + r) * 768 + db + c * 8];
        }
        {
            const int sp = tid & 63, q = tid >> 6;   // q = 0..3
#pragma unroll
            for (int t = 0; t < 3; ++t) {
                const hf8 v = *(const hf8*)&a.proH[(size_t)(pb + sp) * 768 + db + q * 24 + t * 8];
                const hf2x4 w = __builtin_bit_cast(hf2x4, v);
                const int p0 = q * 12 + t * 4;
#pragma unroll
                for (int e = 0; e < 4; ++e)
                    pt[p0 + e][sp] = w.v[e];
            }
        }
        __syncthreads();

        float acc[8][4];
#pragma unroll
        for (int i = 0; i < 8; ++i)
#pragma unroll
            for (int j = 0; j < 4; ++j) acc[i][j] = 0.f;

        const hf2 one2 = {(_Float16)1.0f, (_Float16)1.0f};
#pragma unroll 2
        for (int g = 0; g < 12; ++g) {
            hf2x4 F2[8];
#pragma unroll
            for (int i = 0; i < 8; ++i)
                F2[i] = __builtin_bit_cast(hf2x4, *(const hf8*)&fs[tr + 16 * i][g * 8]);
            hf2x4 P2[4];
#pragma unroll
            for (int q = 0; q < 4; ++q)
                P2[q] = __builtin_bit_cast(hf2x4, *(const hf8*)&pt[g * 4 + q][tp * 4]);
#pragma unroll
            for (int q = 0; q < 4; ++q) {
#pragma unroll
                for (int j = 0; j < 4; ++j) {
                    const hf2 pj = P2[q].v[j];
#pragma unroll
                    for (int i = 0; i < 8; ++i) {
                        hf2 d = F2[i].v[q] - pj;
                        unsigned ud = __builtin_bit_cast(unsigned, d) & 0x7FFF7FFFu;
                        acc[i][j] = FDOT2(__builtin_bit_cast(hf2, ud), one2, acc[i][j]);
                    }
                }
            }
        }
        const int p = pb + tp * 4;
        if (p < 200) {
#pragma unroll
            for (int i = 0; i < 8; ++i) {
                float4 v = {-acc[i][0], -acc[i][1], -acc[i][2], -acc[i][3]};
                *(float4*)&a.part[((size_t)(rb + tr + 16 * i) * 8 + z) * 200 + p] = v;
            }
        }
    }
    __threadfence();
    grid.sync();
    __threadfence();

    // ---- phase 5: reduce (4 rows/block) ----
    if (tid < 200) {
#pragma unroll
        for (int r = 0; r < 4; ++r) {
            const int row = bid * 4 + r;
            float s = 0.f;
#pragma unroll
            for (int z = 0; z < 8; ++z)
                s += a.part[((size_t)row * 8 + z) * 200 + tid];
            a.out[(size_t)row * 200 + tid] = s;
        }
    }
}

// ---------------------------------------------------------------------------
// Workspace layout (bytes). PART (13.1 MB, phase 4+) aliases the GEMM-era
// scratch (xb..adFH, dead by phase 4). featH/proH live above.
// ---------------------------------------------------------------------------
static constexpr size_t OFF_PART  = 0;          // 2048 x 8 x 200 f32 partials
static constexpr size_t OFF_XB    = 0;          // 2048x768 bf16
static constexpr size_t OFF_AWB   = 3145728;
static constexpr size_t OFF_WD0   = 4325376;
static constexpr size_t OFF_WD1   = 4915200;
static constexpr size_t OFF_WD2   = 5062656;
static constexpr size_t OFF_WD3   = 5111808;
static constexpr size_t OFF_WU0   = 5128192;
static constexpr size_t OFF_WU1   = 5144576;
static constexpr size_t OFF_WU2   = 5193728;
static constexpr size_t OFF_WU3   = 5341184;
static constexpr size_t OFF_H1    = 5931008;    // 2048x384 bf16
static constexpr size_t OFF_U2    = 10387456;   // 2048x384 bf16
static constexpr size_t OFF_ADF   = 11960320;   // 2048x768 f16
static constexpr size_t OFF_FEATH = 19660800;   // 2048x768 f16
static constexpr size_t OFF_PROH  = 22806528;   // 256x768 f16

extern "C" void kernel_launch(void* const* d_in, const int* in_sizes, int n_in,
                              void* d_out, int out_size, void* d_ws, size_t ws_size,
                              hipStream_t stream) {
    const float* x      = (const float*)d_in[0];
    const float* aW     = (const float*)d_in[1];
    const float* ab     = (const float*)d_in[2];
    const float* protos = (const float*)d_in[3];
    const float* Wd[4]  = {(const float*)d_in[4], (const float*)d_in[6],
                           (const float*)d_in[8], (const float*)d_in[10]};
    const float* bd[4]  = {(const float*)d_in[5], (const float*)d_in[7],
                           (const float*)d_in[9], (const float*)d_in[11]};
    const float* Wu[4]  = {(const float*)d_in[12], (const float*)d_in[14],
                           (const float*)d_in[16], (const float*)d_in[18]};
    const float* bu[4]  = {(const float*)d_in[13], (const float*)d_in[15],
                           (const float*)d_in[17], (const float*)d_in[19]};
    char* ws = (char*)d_ws;

    MegaArgs ma;
    int blk = 0;
    auto set = [&](int i, const float* s, u16* d, int N, int K, int Np, int Kp,
                   int fmt) {
        ma.tab.t[i] = {s, d, N, K, Np, Kp, blk, fmt};
        blk += (Np * Kp + 255) / 256;
    };
    u16* xb   = (u16*)(ws + OFF_XB);
    _Float16* proH = (_Float16*)(ws + OFF_PROH);
    set(0,  x,      xb,                   2048, 768, 2048, 768, 0);
    set(1,  aW,     (u16*)(ws + OFF_AWB), 768,  768, 768,  768, 0);
    set(2,  Wd[0],  (u16*)(ws + OFF_WD0), 384,  768, 384,  768, 0);
    set(3,  Wd[1],  (u16*)(ws + OFF_WD1), 192,  384, 192,  384, 0);
    set(4,  Wd[2],  (u16*)(ws + OFF_WD2), 96,   192, 128,  192, 0);
    set(5,  Wd[3],  (u16*)(ws + OFF_WD3), 48,   96,  64,   128, 0);
    set(6,  Wu[0],  (u16*)(ws + OFF_WU0), 96,   48,  128,  64,  0);
    set(7,  Wu[1],  (u16*)(ws + OFF_WU1), 192,  96,  192,  128, 0);
    set(8,  Wu[2],  (u16*)(ws + OFF_WU2), 384,  192, 384,  192, 0);
    set(9,  Wu[3],  (u16*)(ws + OFF_WU3), 768,  384, 768,  384, 0);
    set(10, protos, (u16*)proH,           200,  768, 256,  768, 1);
    ma.cvt_blocks = blk;

    ma.xb = xb;
    ma.aWb  = (const u16*)(ws + OFF_AWB);
    ma.Wd0b = (const u16*)(ws + OFF_WD0);
    ma.Wd1b = (const u16*)(ws + OFF_WD1);
    ma.Wd2b = (const u16*)(ws + OFF_WD2);
    ma.Wd3b = (const u16*)(ws + OFF_WD3);
    ma.Wu0b = (const u16*)(ws + OFF_WU0);
    ma.Wu1b = (const u16*)(ws + OFF_WU1);
    ma.Wu2b = (const u16*)(ws + OFF_WU2);
    ma.Wu3b = (const u16*)(ws + OFF_WU3);
    ma.ab = ab;
    ma.bd0 = bd[0]; ma.bd1 = bd[1]; ma.bd2 = bd[2]; ma.bd3 = bd[3];
    ma.bu0 = bu[0]; ma.bu1 = bu[1]; ma.bu2 = bu[2]; ma.bu3 = bu[3];
    ma.h1 = (u16*)(ws + OFF_H1);
    ma.u2 = (u16*)(ws + OFF_U2);
    ma.adFH  = (_Float16*)(ws + OFF_ADF);
    ma.featH = (_Float16*)(ws + OFF_FEATH);
    ma.proH  = proH;
    ma.part  = (float*)(ws + OFF_PART);
    ma.out   = (float*)d_out;

    void* kargs[] = { &ma };
    (void)hipLaunchCooperativeKernel((const void*)mega, dim3(512), dim3(256),
                                     kargs, 0, stream);
}

// Round 10
// 80.787 us; speedup vs baseline: 9.6643x; 9.6643x over previous
//
#include <hip/hip_runtime.h>

typedef __attribute__((ext_vector_type(8))) __bf16 bf16x8;
typedef __attribute__((ext_vector_type(4))) float f32x4;
typedef _Float16 hf2 __attribute__((ext_vector_type(2)));
typedef _Float16 hf8 __attribute__((ext_vector_type(8)));
typedef unsigned short u16;
typedef struct { hf2 v[4]; } hf2x4;   // register-friendly view of hf8

__device__ __forceinline__ float bf2f(u16 h) {
    return __uint_as_float(((unsigned int)h) << 16);
}
__device__ __forceinline__ u16 f2bf(float f) {
    unsigned int u = __float_as_uint(f);
    u += 0x7fffu + ((u >> 16) & 1u);   // RNE
    return (u16)(u >> 16);
}

#if __has_builtin(__builtin_amdgcn_fdot2)
__device__ __forceinline__ float FDOT2(hf2 a, hf2 b, float c) {
    return __builtin_amdgcn_fdot2(a, b, c, false);
}
#else
__device__ __forceinline__ float FDOT2(hf2 a, hf2 b, float c) {
    return c + (float)a[0] + (float)a[1];   // b is all-ones in our use
}
#endif

#define GLOAD_LDS16(gsrc, ldst)                                                          \
    __builtin_amdgcn_global_load_lds(                                                    \
        (__attribute__((address_space(1))) unsigned int*)(gsrc),                         \
        (__attribute__((address_space(3))) unsigned int*)(ldst), 16, 0, 0)

// ---------------------------------------------------------------------------
// f32 -> bf16/f16 convert with zero-padding. Unused tab entries: blk0=INT_MAX.
// ---------------------------------------------------------------------------
struct CvtDesc { const float* src; u16* dst; int N, K, Npad, Kpad, blk0, fmt; };
struct CvtTab { CvtDesc t[11]; };

__device__ __forceinline__ void do_cvt(const CvtTab& tab, int vb, int tid) {
    int ti = 0;
#pragma unroll
    for (int j = 1; j < 11; ++j)
        if (vb >= tab.t[j].blk0) ti = j;
    const CvtDesc c = tab.t[ti];
    long i = (long)(vb - c.blk0) * 256 + tid;
    long tot = (long)c.Npad * c.Kpad;
    if (i >= tot) return;
    int n = (int)(i / c.Kpad);
    int k = (int)(i - (long)n * c.Kpad);
    float v = (n < c.N && k < c.K) ? c.src[(long)n * c.K + k] : 0.f;
    c.dst[i] = c.fmt ? __builtin_bit_cast(u16, (_Float16)v) : f2bf(v);
}

__global__ __launch_bounds__(256) void cvt_k(CvtTab tab) {
    do_cvt(tab, blockIdx.x, threadIdx.x);
}

// ---------------------------------------------------------------------------
// 128x64-tile double-buffered bf16 MFMA GEMM (2-phase pipeline): STAGE(next)
// issued BEFORE COMPUTE(cur); one vmcnt-drain barrier per K-step.
// 256 thr = 4 waves as 2x2 over (128,64); wave tile 64x32 = acc[4][2].
// XOR-swizzled granules via pre-swizzled global source + linear LDS dest.
// ---------------------------------------------------------------------------
template<int RELU>
__device__ __forceinline__ void gemm128_body(
    char* lds,
    const u16* __restrict__ A, int lda,
    const u16* __restrict__ W, int ldw,
    const float* __restrict__ bias,
    u16* __restrict__ outB, int ldo,
    int nk, int mb, int nb)
{
    const int tid = threadIdx.x;
    const int wave = tid >> 6, lane = tid & 63;
    const int lr = lane & 15, lk = lane >> 4;
    const int wr = wave >> 1, wc = wave & 1;

    f32x4 acc[4][2];
#pragma unroll
    for (int i = 0; i < 4; ++i)
#pragma unroll
        for (int j = 0; j < 2; ++j)
#pragma unroll
            for (int e = 0; e < 4; ++e) acc[i][j][e] = 0.f;

    int ra[4], la[4], rb_[2], lb[2];
#pragma unroll
    for (int t = 0; t < 4; ++t) {
        int g = t * 256 + tid;
        ra[t] = g >> 3; la[t] = (g & 7) ^ (ra[t] & 7);
    }
#pragma unroll
    for (int t = 0; t < 2; ++t) {
        int g = t * 256 + tid;
        rb_[t] = g >> 3; lb[t] = (g & 7) ^ (rb_[t] & 7);
    }

    auto STAGE = [&](int b, int kt) {
        const int kk = kt * 64;
        char* dA = lds + b * 24576;
        char* dB = dA + 16384;
#pragma unroll
        for (int t = 0; t < 4; ++t)
            GLOAD_LDS16(A + (size_t)(mb + ra[t]) * lda + kk + la[t] * 8,
                        dA + t * 4096 + wave * 1024);
#pragma unroll
        for (int t = 0; t < 2; ++t)
            GLOAD_LDS16(W + (size_t)(nb + rb_[t]) * ldw + kk + lb[t] * 8,
                        dB + t * 4096 + wave * 1024);
    };
    auto COMPUTE = [&](int b) {
        char* sA = lds + b * 24576;
        char* sB = sA + 16384;
#pragma unroll
        for (int ks = 0; ks < 2; ++ks) {
            bf16x8 af[4], bfr[2];
#pragma unroll
            for (int mi = 0; mi < 4; ++mi) {
                int m_loc = wr * 64 + mi * 16 + lr;
                int gr = (ks * 4 + lk) ^ (m_loc & 7);
                af[mi] = *(const bf16x8*)(sA + m_loc * 128 + gr * 16);
            }
#pragma unroll
            for (int ni = 0; ni < 2; ++ni) {
                int n_loc = wc * 32 + ni * 16 + lr;
                int gr = (ks * 4 + lk) ^ (n_loc & 7);
                bfr[ni] = *(const bf16x8*)(sB + n_loc * 128 + gr * 16);
            }
#pragma unroll
            for (int mi = 0; mi < 4; ++mi)
#pragma unroll
                for (int ni = 0; ni < 2; ++ni)
                    acc[mi][ni] = __builtin_amdgcn_mfma_f32_16x16x32_bf16(
                        af[mi], bfr[ni], acc[mi][ni], 0, 0, 0);
        }
    };

    STAGE(0, 0);
    __syncthreads();
    int b = 0;
    for (int kt = 0; kt < nk - 1; ++kt) {
        STAGE(b ^ 1, kt + 1);
        COMPUTE(b);
        __syncthreads();
        b ^= 1;
    }
    COMPUTE(b);

    // epilogue: C/D layout col = lane&15, row = (lane>>4)*4 + reg
#pragma unroll
    for (int mi = 0; mi < 4; ++mi) {
#pragma unroll
        for (int ni = 0; ni < 2; ++ni) {
            const int n_g = nb + wc * 32 + ni * 16 + lr;
            const float bv = bias[n_g];
#pragma unroll
            for (int r = 0; r < 4; ++r) {
                const int m_g = mb + wr * 64 + mi * 16 + lk * 4 + r;
                float v = acc[mi][ni][r] + bv;
                if (RELU) v = fmaxf(v, 0.f);
                outB[(size_t)m_g * ldo + n_g] = f2bf(v);
            }
        }
    }
}

// launch 2: down0 (h1 = relu(x@Wd0.T+bd0), 96 tiles) + rest-of-cvt (grid-stride)
__global__ __launch_bounds__(256, 2) void gemm_d0_cvt(
    const u16* __restrict__ xb, const u16* __restrict__ Wd0b,
    const float* __restrict__ bd0, u16* __restrict__ h1, CvtTab tabB)
{
    __shared__ __align__(16) char lds[49152];
    const int bid = blockIdx.x;
    if (bid < 96) {
        gemm128_body<1>(lds, xb, 768, Wd0b, 768, bd0, h1, 384, 12,
                        (bid & 15) * 128, (bid >> 4) * 64);
    } else {
        do_cvt(tabB, bid - 96, threadIdx.x);
    }
}

// ---------------------------------------------------------------------------
// launch 4: u3+adapter fused. featH = f16( relu(u2@Wu3.T + bu3)
//                                          + x@aW.T + ab + x )
// Two K-phases into one accumulator: phase1 = u2/Wu3 (6 K-steps), then
// acc = relu(acc + bu3); phase2 += x/aW (12 K-steps); epilogue + ab + x.
// Same 128x64 dbuf pipeline; grid (16, 12).
// ---------------------------------------------------------------------------
__global__ __launch_bounds__(256, 2) void gemm_u3ad(
    const u16* __restrict__ u2, const u16* __restrict__ Wu3b,
    const float* __restrict__ bu3,
    const u16* __restrict__ xb, const u16* __restrict__ aWb,
    const float* __restrict__ ab,
    _Float16* __restrict__ featH)
{
    __shared__ __align__(16) char lds[49152];
    const int mb = blockIdx.x * 128, nb = blockIdx.y * 64;
    const int tid = threadIdx.x;
    const int wave = tid >> 6, lane = tid & 63;
    const int lr = lane & 15, lk = lane >> 4;
    const int wr = wave >> 1, wc = wave & 1;

    f32x4 acc[4][2];
#pragma unroll
    for (int i = 0; i < 4; ++i)
#pragma unroll
        for (int j = 0; j < 2; ++j)
#pragma unroll
            for (int e = 0; e < 4; ++e) acc[i][j][e] = 0.f;

    int ra[4], la[4], rb_[2], lb[2];
#pragma unroll
    for (int t = 0; t < 4; ++t) {
        int g = t * 256 + tid;
        ra[t] = g >> 3; la[t] = (g & 7) ^ (ra[t] & 7);
    }
#pragma unroll
    for (int t = 0; t < 2; ++t) {
        int g = t * 256 + tid;
        rb_[t] = g >> 3; lb[t] = (g & 7) ^ (rb_[t] & 7);
    }

    auto STAGE = [&](int b, int kt) {
        const u16* A; const u16* W; int ld, kk;
        if (kt < 6) { A = u2; W = Wu3b; ld = 384; kk = kt * 64; }
        else        { A = xb; W = aWb;  ld = 768; kk = (kt - 6) * 64; }
        char* dA = lds + b * 24576;
        char* dB = dA + 16384;
#pragma unroll
        for (int t = 0; t < 4; ++t)
            GLOAD_LDS16(A + (size_t)(mb + ra[t]) * ld + kk + la[t] * 8,
                        dA + t * 4096 + wave * 1024);
#pragma unroll
        for (int t = 0; t < 2; ++t)
            GLOAD_LDS16(W + (size_t)(nb + rb_[t]) * ld + kk + lb[t] * 8,
                        dB + t * 4096 + wave * 1024);
    };
    auto COMPUTE = [&](int b) {
        char* sA = lds + b * 24576;
        char* sB = sA + 16384;
#pragma unroll
        for (int ks = 0; ks < 2; ++ks) {
            bf16x8 af[4], bfr[2];
#pragma unroll
            for (int mi = 0; mi < 4; ++mi) {
                int m_loc = wr * 64 + mi * 16 + lr;
                int gr = (ks * 4 + lk) ^ (m_loc & 7);
                af[mi] = *(const bf16x8*)(sA + m_loc * 128 + gr * 16);
            }
#pragma unroll
            for (int ni = 0; ni < 2; ++ni) {
                int n_loc = wc * 32 + ni * 16 + lr;
                int gr = (ks * 4 + lk) ^ (n_loc & 7);
                bfr[ni] = *(const bf16x8*)(sB + n_loc * 128 + gr * 16);
            }
#pragma unroll
            for (int mi = 0; mi < 4; ++mi)
#pragma unroll
                for (int ni = 0; ni < 2; ++ni)
                    acc[mi][ni] = __builtin_amdgcn_mfma_f32_16x16x32_bf16(
                        af[mi], bfr[ni], acc[mi][ni], 0, 0, 0);
        }
    };

    STAGE(0, 0);
    __syncthreads();
    int b = 0;
    for (int kt = 0; kt < 17; ++kt) {
        STAGE(b ^ 1, kt + 1);
        COMPUTE(b);
        if (kt == 5) {
            // phase-1 (u3 GEMM) complete: r = relu(acc + bu3)
#pragma unroll
            for (int mi = 0; mi < 4; ++mi)
#pragma unroll
                for (int ni = 0; ni < 2; ++ni) {
                    const int n_g = nb + wc * 32 + ni * 16 + lr;
                    const float bv = bu3[n_g];
#pragma unroll
                    for (int r = 0; r < 4; ++r)
                        acc[mi][ni][r] = fmaxf(acc[mi][ni][r] + bv, 0.f);
                }
        }
        __syncthreads();
        b ^= 1;
    }
    COMPUTE(b);

    // epilogue: + ab + x (bf16), write f16
#pragma unroll
    for (int mi = 0; mi < 4; ++mi) {
#pragma unroll
        for (int ni = 0; ni < 2; ++ni) {
            const int n_g = nb + wc * 32 + ni * 16 + lr;
            const float bv = ab[n_g];
#pragma unroll
            for (int r = 0; r < 4; ++r) {
                const int m_g = mb + wr * 64 + mi * 16 + lk * 4 + r;
                float v = acc[mi][ni][r] + bv + bf2f(xb[(size_t)m_g * 768 + n_g]);
                featH[(size_t)m_g * 768 + n_g] = (_Float16)v;
            }
        }
    }
}

// ---------------------------------------------------------------------------
// Fused middle chain: d1 -> d2 -> d3 -> u0(+h3) -> u1(+h2) -> u2, one launch.
// 128 blocks x 16 rows, 256 thr. Activations in LDS; weights direct from L2.
// ---------------------------------------------------------------------------
template<int K, int NPAD, int NREAL, int RES, int OUTG>
__device__ __forceinline__ void layer16(
    const u16* __restrict__ W, int ldw, const float* __restrict__ bias,
    const u16* actIn, int ldin,
    u16* actOut, int ldout,
    const u16* resid, int ldres,
    u16* __restrict__ gout, int ldg)
{
    constexpr int TPW = NPAD / 64;
    const int tid = threadIdx.x;
    const int wave = tid >> 6, lane = tid & 63;
    const int lr = lane & 15, lk = lane >> 4;

    f32x4 acc[TPW];
#pragma unroll
    for (int t = 0; t < TPW; ++t)
#pragma unroll
        for (int e = 0; e < 4; ++e) acc[t][e] = 0.f;

#pragma unroll
    for (int kk = 0; kk < K / 32; ++kk) {
        const bf16x8 a = *(const bf16x8*)&actIn[lr * ldin + kk * 32 + lk * 8];
#pragma unroll
        for (int t = 0; t < TPW; ++t) {
            const int nc = (wave * TPW + t) * 16 + lr;
            const bf16x8 b = *(const bf16x8*)&W[(size_t)nc * ldw + kk * 32 + lk * 8];
            acc[t] = __builtin_amdgcn_mfma_f32_16x16x32_bf16(a, b, acc[t], 0, 0, 0);
        }
    }
#pragma unroll
    for (int t = 0; t < TPW; ++t) {
        const int nc = (wave * TPW + t) * 16 + lr;
        const float bv = (nc < NREAL) ? bias[nc] : 0.f;
#pragma unroll
        for (int r = 0; r < 4; ++r) {
            const int row = lk * 4 + r;
            float v = fmaxf(acc[t][r] + bv, 0.f);
            if (RES) v += bf2f(resid[row * ldres + nc]);
            const u16 o = f2bf(v);
            if (OUTG) gout[(size_t)row * ldg + nc] = o;
            else      actOut[row * ldout + nc] = o;
        }
    }
}

__global__ __launch_bounds__(256) void chain_mid(
    const u16* __restrict__ h1,
    const u16* __restrict__ Wd1b, const float* __restrict__ bd1,
    const u16* __restrict__ Wd2b, const float* __restrict__ bd2,
    const u16* __restrict__ Wd3b, const float* __restrict__ bd3,
    const u16* __restrict__ Wu0b, const float* __restrict__ bu0,
    const u16* __restrict__ Wu1b, const float* __restrict__ bu1,
    const u16* __restrict__ Wu2b, const float* __restrict__ bu2,
    u16* __restrict__ u2)
{
    __shared__ u16 As[16 * 392];  // h1 in; later E=[0..16*136) u0out, F u1out
    __shared__ u16 Bs[16 * 200];  // h2 skip (192w)
    __shared__ u16 Cs[16 * 136];  // h3 skip (128w, cols 96.. = 0)
    __shared__ u16 Ds[16 * 72];   // h4 (64w, cols 48.. = 0)
    const int tid = threadIdx.x;
    const int rb = blockIdx.x * 16;

    for (int i = tid; i < 768; i += 256) {
        const int r = i / 48, c = i - r * 48;
        *(bf16x8*)&As[r * 392 + c * 8] =
            *(const bf16x8*)&h1[(size_t)(rb + r) * 384 + c * 8];
    }
    __syncthreads();
    layer16<384, 192, 192, 0, 0>(Wd1b, 384, bd1, As, 392, Bs, 200, nullptr, 0, nullptr, 0);
    __syncthreads();
    layer16<192, 128,  96, 0, 0>(Wd2b, 192, bd2, Bs, 200, Cs, 136, nullptr, 0, nullptr, 0);
    __syncthreads();
    layer16<128,  64,  48, 0, 0>(Wd3b, 128, bd3, Cs, 136, Ds,  72, nullptr, 0, nullptr, 0);
    __syncthreads();
    u16* E = As;                 // 16 x 136
    u16* F = As + 16 * 136;      // 16 x 200
    layer16< 64, 128,  96, 1, 0>(Wu0b,  64, bu0, Ds,  72, E, 136, Cs, 136, nullptr, 0);
    __syncthreads();
    layer16<128, 192, 192, 1, 0>(Wu1b, 128, bu1, E, 136, F, 200, Bs, 200, nullptr, 0);
    __syncthreads();
    layer16<192, 384, 384, 0, 1>(Wu2b, 192, bu2, F, 200, nullptr, 0, nullptr, 0,
                                 u2 + (size_t)rb * 384, 384);
}

// ---------------------------------------------------------------------------
// L1 head: part[row][z][p] = sum_{d in chunk z} -|feat[row][d] - protos[p][d]|
// Grid (16 rb, 4 pb, 12 z). Block: 128 rows x 64 protos x 64 d.
// Non-atomic coalesced float4 stores (atomics were the R4 bottleneck).
// ---------------------------------------------------------------------------
__global__ __launch_bounds__(256) void l1_kernel(
    const _Float16* __restrict__ feat, const _Float16* __restrict__ protos,
    float* __restrict__ part)
{
    __shared__ _Float16 fs[128][64];
    __shared__ hf2 pt[32][64];        // [d-pair][proto]
    const int tid = threadIdx.x;
    const int tp = tid & 15, tr = tid >> 4;
    const int rb = blockIdx.x * 128;
    const int pb = blockIdx.y * 64;
    const int db = blockIdx.z * 64;

    {
        const int g = tid & 7, r0 = tid >> 3;
#pragma unroll
        for (int k = 0; k < 4; ++k) {
            const int r = r0 + 32 * k;
            *(hf8*)&fs[r][g * 8] =
                *(const hf8*)&feat[(size_t)(rb + r) * 768 + db + g * 8];
        }
    }
    {
        const int sp = tid & 63, q = tid >> 6;
        const _Float16* src = &protos[(size_t)(pb + sp) * 768 + db + q * 16];
        hf8 v0 = *(const hf8*)src;
        hf8 v1 = *(const hf8*)(src + 8);
        hf2x4 w0 = __builtin_bit_cast(hf2x4, v0);
        hf2x4 w1 = __builtin_bit_cast(hf2x4, v1);
#pragma unroll
        for (int e = 0; e < 4; ++e)
            pt[q * 8 + e][sp] = w0.v[e];
#pragma unroll
        for (int e = 0; e < 4; ++e)
            pt[q * 8 + 4 + e][sp] = w1.v[e];
    }
    __syncthreads();

    float acc[8][4];
#pragma unroll
    for (int i = 0; i < 8; ++i)
#pragma unroll
        for (int j = 0; j < 4; ++j) acc[i][j] = 0.f;

    const hf2 one2 = {(_Float16)1.0f, (_Float16)1.0f};
#pragma unroll 2
    for (int g = 0; g < 8; ++g) {
        hf2x4 F2[8];
#pragma unroll
        for (int i = 0; i < 8; ++i)
            F2[i] = __builtin_bit_cast(hf2x4,
                        *(const hf8*)&fs[tr + 16 * i][g * 8]);
        hf2x4 P2[4];
#pragma unroll
        for (int q = 0; q < 4; ++q)
            P2[q] = __builtin_bit_cast(hf2x4,
                        *(const hf8*)&pt[g * 4 + q][tp * 4]);
#pragma unroll
        for (int q = 0; q < 4; ++q) {
#pragma unroll
            for (int j = 0; j < 4; ++j) {
                const hf2 pj = P2[q].v[j];
#pragma unroll
                for (int i = 0; i < 8; ++i) {
                    hf2 d = F2[i].v[q] - pj;
                    unsigned ud = __builtin_bit_cast(unsigned, d) & 0x7FFF7FFFu;
                    acc[i][j] = FDOT2(__builtin_bit_cast(hf2, ud), one2, acc[i][j]);
                }
            }
        }
    }
    const int p = pb + tp * 4;
    if (p < 200) {
#pragma unroll
        for (int i = 0; i < 8; ++i) {
            float4 v = {-acc[i][0], -acc[i][1], -acc[i][2], -acc[i][3]};
            *(float4*)&part[((size_t)(rb + tr + 16 * i) * 12 + blockIdx.z) * 200 + p] = v;
        }
    }
}

__global__ __launch_bounds__(256) void l1_reduce(
    const float* __restrict__ part, float* __restrict__ out)
{
    const int row = blockIdx.x;
    const int p = threadIdx.x;
    if (p < 200) {
        float s = 0.f;
#pragma unroll
        for (int z = 0; z < 12; ++z)
            s += part[((size_t)row * 12 + z) * 200 + p];
        out[(size_t)row * 200 + p] = s;
    }
}

// ---------------------------------------------------------------------------
// Workspace layout (bytes). PART (19.66 MB) aliases GEMM-era scratch.
// ---------------------------------------------------------------------------
static constexpr size_t OFF_PART  = 0;          // 2048 x 12 x 200 f32 partials
static constexpr size_t OFF_XB    = 0;          // 2048x768 bf16
static constexpr size_t OFF_AWB   = 3145728;
static constexpr size_t OFF_WD0   = 4325376;
static constexpr size_t OFF_WD1   = 4915200;
static constexpr size_t OFF_WD2   = 5062656;
static constexpr size_t OFF_WD3   = 5111808;
static constexpr size_t OFF_WU0   = 5128192;
static constexpr size_t OFF_WU1   = 5144576;
static constexpr size_t OFF_WU2   = 5193728;
static constexpr size_t OFF_WU3   = 5341184;
static constexpr size_t OFF_H1    = 5931008;    // 2048x384 bf16
static constexpr size_t OFF_U2    = 10387456;   // 2048x384 bf16
static constexpr size_t OFF_FEATH = 19660800;   // 2048x768 f16
static constexpr size_t OFF_PROH  = 22806528;   // 256x768 f16

extern "C" void kernel_launch(void* const* d_in, const int* in_sizes, int n_in,
                              void* d_out, int out_size, void* d_ws, size_t ws_size,
                              hipStream_t stream) {
    const float* x      = (const float*)d_in[0];
    const float* aW     = (const float*)d_in[1];
    const float* ab     = (const float*)d_in[2];
    const float* protos = (const float*)d_in[3];
    const float* Wd[4]  = {(const float*)d_in[4], (const float*)d_in[6],
                           (const float*)d_in[8], (const float*)d_in[10]};
    const float* bd[4]  = {(const float*)d_in[5], (const float*)d_in[7],
                           (const float*)d_in[9], (const float*)d_in[11]};
    const float* Wu[4]  = {(const float*)d_in[12], (const float*)d_in[14],
                           (const float*)d_in[16], (const float*)d_in[18]};
    const float* bu[4]  = {(const float*)d_in[13], (const float*)d_in[15],
                           (const float*)d_in[17], (const float*)d_in[19]};
    float* out = (float*)d_out;
    char* ws = (char*)d_ws;

    u16* xb    = (u16*)(ws + OFF_XB);
    u16* aWb   = (u16*)(ws + OFF_AWB);
    u16* Wd0b  = (u16*)(ws + OFF_WD0);
    u16* Wd1b  = (u16*)(ws + OFF_WD1);
    u16* Wd2b  = (u16*)(ws + OFF_WD2);
    u16* Wd3b  = (u16*)(ws + OFF_WD3);
    u16* Wu0b  = (u16*)(ws + OFF_WU0);
    u16* Wu1b  = (u16*)(ws + OFF_WU1);
    u16* Wu2b  = (u16*)(ws + OFF_WU2);
    u16* Wu3b  = (u16*)(ws + OFF_WU3);
    u16* h1    = (u16*)(ws + OFF_H1);
    u16* u2    = (u16*)(ws + OFF_U2);
    float* part = (float*)(ws + OFF_PART);
    _Float16* featH = (_Float16*)(ws + OFF_FEATH);
    _Float16* proH  = (_Float16*)(ws + OFF_PROH);

    const int SENT = 0x7FFFFFFF;

    // --- launch 1: cvt of down0 deps only (x, Wd0) ---
    CvtTab tabA;
    int blkA = 0;
    tabA.t[0] = {x,     xb,   2048, 768, 2048, 768, 0, 0};
    blkA += 2048 * 768 / 256;
    tabA.t[1] = {Wd[0], Wd0b, 384,  768, 384,  768, blkA, 0};
    blkA += 384 * 768 / 256;
    for (int j = 2; j < 11; ++j) tabA.t[j].blk0 = SENT;
    cvt_k<<<blkA, 256, 0, stream>>>(tabA);

    // --- launch 2: down0 (96 tiles) + cvt of everything else ---
    CvtTab tabB;
    int blkB = 0;
    auto setB = [&](int i, const float* s, u16* d, int N, int K, int Np, int Kp,
                    int fmt) {
        tabB.t[i] = {s, d, N, K, Np, Kp, blkB, fmt};
        blkB += (Np * Kp + 255) / 256;
    };
    setB(0, aW,     aWb,        768, 768, 768, 768, 0);
    setB(1, Wd[1],  Wd1b,       192, 384, 192, 384, 0);
    setB(2, Wd[2],  Wd2b,       96,  192, 128, 192, 0);
    setB(3, Wd[3],  Wd3b,       48,  96,  64,  128, 0);
    setB(4, Wu[0],  Wu0b,       96,  48,  128, 64,  0);
    setB(5, Wu[1],  Wu1b,       192, 96,  192, 128, 0);
    setB(6, Wu[2],  Wu2b,       384, 192, 384, 192, 0);
    setB(7, Wu[3],  Wu3b,       768, 384, 768, 384, 0);
    setB(8, protos, (u16*)proH, 200, 768, 256, 768, 1);
    for (int j = 9; j < 11; ++j) tabB.t[j].blk0 = SENT;
    gemm_d0_cvt<<<96 + blkB, 256, 0, stream>>>(xb, Wd0b, bd[0], h1, tabB);

    // --- launch 3: chain d1..u2 ---
    chain_mid<<<dim3(128), 256, 0, stream>>>(h1,
        Wd1b, bd[1], Wd2b, bd[2], Wd3b, bd[3],
        Wu0b, bu[0], Wu1b, bu[1], Wu2b, bu[2], u2);

    // --- launch 4: u3 + adapter fused -> featH ---
    gemm_u3ad<<<dim3(16, 12), 256, 0, stream>>>(u2, Wu3b, bu[3],
                                                xb, aWb, ab, featH);

    // --- launch 5+6: L1 head partials, then reduce ---
    l1_kernel<<<dim3(16, 4, 12), 256, 0, stream>>>(featH, proH, part);
    l1_reduce<<<dim3(2048), 256, 0, stream>>>(part, out);
}

// Round 11
// 79.075 us; speedup vs baseline: 9.8735x; 1.0216x over previous
//
#include <hip/hip_runtime.h>

typedef __attribute__((ext_vector_type(8))) __bf16 bf16x8;
typedef __attribute__((ext_vector_type(4))) float f32x4;
typedef _Float16 hf2 __attribute__((ext_vector_type(2)));
typedef _Float16 hf8 __attribute__((ext_vector_type(8)));
typedef unsigned short u16;
typedef struct { hf2 v[4]; } hf2x4;   // register-friendly view of hf8

__device__ __forceinline__ float bf2f(u16 h) {
    return __uint_as_float(((unsigned int)h) << 16);
}
__device__ __forceinline__ u16 f2bf(float f) {
    unsigned int u = __float_as_uint(f);
    u += 0x7fffu + ((u >> 16) & 1u);   // RNE
    return (u16)(u >> 16);
}

#if __has_builtin(__builtin_amdgcn_fdot2)
__device__ __forceinline__ float FDOT2(hf2 a, hf2 b, float c) {
    return __builtin_amdgcn_fdot2(a, b, c, false);
}
#else
__device__ __forceinline__ float FDOT2(hf2 a, hf2 b, float c) {
    return c + (float)a[0] + (float)a[1];   // b is all-ones in our use
}
#endif

#define GLOAD_LDS16(gsrc, ldst)                                                          \
    __builtin_amdgcn_global_load_lds(                                                    \
        (__attribute__((address_space(1))) unsigned int*)(gsrc),                         \
        (__attribute__((address_space(3))) unsigned int*)(ldst), 16, 0, 0)

// ---------------------------------------------------------------------------
// f32 -> bf16/f16 convert with zero-padding. Unused tab entries: blk0=INT_MAX.
// ---------------------------------------------------------------------------
struct CvtDesc { const float* src; u16* dst; int N, K, Npad, Kpad, blk0, fmt; };
struct CvtTab { CvtDesc t[11]; };

__device__ __forceinline__ void do_cvt(const CvtTab& tab, int vb, int tid) {
    int ti = 0;
#pragma unroll
    for (int j = 1; j < 11; ++j)
        if (vb >= tab.t[j].blk0) ti = j;
    const CvtDesc c = tab.t[ti];
    long i = (long)(vb - c.blk0) * 256 + tid;
    long tot = (long)c.Npad * c.Kpad;
    if (i >= tot) return;
    int n = (int)(i / c.Kpad);
    int k = (int)(i - (long)n * c.Kpad);
    float v = (n < c.N && k < c.K) ? c.src[(long)n * c.K + k] : 0.f;
    c.dst[i] = c.fmt ? __builtin_bit_cast(u16, (_Float16)v) : f2bf(v);
}

__global__ __launch_bounds__(256) void cvt_k(CvtTab tab) {
    do_cvt(tab, blockIdx.x, threadIdx.x);
}

// ---------------------------------------------------------------------------
// 128x64-tile double-buffered bf16 MFMA GEMM (2-phase pipeline): STAGE(next)
// issued BEFORE COMPUTE(cur); one vmcnt-drain barrier per K-step.
// 256 thr = 4 waves as 2x2 over (128,64); wave tile 64x32 = acc[4][2].
// XOR-swizzled granules via pre-swizzled global source + linear LDS dest.
// Epilogue: v = acc + bias; if RELU relu; if HASRES += res (bf16 or f16);
// MODE 0 -> bf16 outB (ldo), MODE 2 -> f16 outH (stride 768).
// ---------------------------------------------------------------------------
template<int RELU, int HASRES, int RESF16, int MODE>
__device__ __forceinline__ void gemm128_body(
    char* lds,
    const u16* __restrict__ A, int lda,
    const u16* __restrict__ W, int ldw,
    const float* __restrict__ bias,
    u16* __restrict__ outB, int ldo,
    const void* __restrict__ res, int ldr,
    _Float16* __restrict__ outH,
    int nk, int mb, int nb)
{
    const int tid = threadIdx.x;
    const int wave = tid >> 6, lane = tid & 63;
    const int lr = lane & 15, lk = lane >> 4;
    const int wr = wave >> 1, wc = wave & 1;

    f32x4 acc[4][2];
#pragma unroll
    for (int i = 0; i < 4; ++i)
#pragma unroll
        for (int j = 0; j < 2; ++j)
#pragma unroll
            for (int e = 0; e < 4; ++e) acc[i][j][e] = 0.f;

    int ra[4], la[4], rb_[2], lb[2];
#pragma unroll
    for (int t = 0; t < 4; ++t) {
        int g = t * 256 + tid;
        ra[t] = g >> 3; la[t] = (g & 7) ^ (ra[t] & 7);
    }
#pragma unroll
    for (int t = 0; t < 2; ++t) {
        int g = t * 256 + tid;
        rb_[t] = g >> 3; lb[t] = (g & 7) ^ (rb_[t] & 7);
    }

    auto STAGE = [&](int b, int kt) {
        const int kk = kt * 64;
        char* dA = lds + b * 24576;
        char* dB = dA + 16384;
#pragma unroll
        for (int t = 0; t < 4; ++t)
            GLOAD_LDS16(A + (size_t)(mb + ra[t]) * lda + kk + la[t] * 8,
                        dA + t * 4096 + wave * 1024);
#pragma unroll
        for (int t = 0; t < 2; ++t)
            GLOAD_LDS16(W + (size_t)(nb + rb_[t]) * ldw + kk + lb[t] * 8,
                        dB + t * 4096 + wave * 1024);
    };
    auto COMPUTE = [&](int b) {
        char* sA = lds + b * 24576;
        char* sB = sA + 16384;
#pragma unroll
        for (int ks = 0; ks < 2; ++ks) {
            bf16x8 af[4], bfr[2];
#pragma unroll
            for (int mi = 0; mi < 4; ++mi) {
                int m_loc = wr * 64 + mi * 16 + lr;
                int gr = (ks * 4 + lk) ^ (m_loc & 7);
                af[mi] = *(const bf16x8*)(sA + m_loc * 128 + gr * 16);
            }
#pragma unroll
            for (int ni = 0; ni < 2; ++ni) {
                int n_loc = wc * 32 + ni * 16 + lr;
                int gr = (ks * 4 + lk) ^ (n_loc & 7);
                bfr[ni] = *(const bf16x8*)(sB + n_loc * 128 + gr * 16);
            }
#pragma unroll
            for (int mi = 0; mi < 4; ++mi)
#pragma unroll
                for (int ni = 0; ni < 2; ++ni)
                    acc[mi][ni] = __builtin_amdgcn_mfma_f32_16x16x32_bf16(
                        af[mi], bfr[ni], acc[mi][ni], 0, 0, 0);
        }
    };

    STAGE(0, 0);
    __syncthreads();
    int b = 0;
    for (int kt = 0; kt < nk - 1; ++kt) {
        STAGE(b ^ 1, kt + 1);
        COMPUTE(b);
        __syncthreads();
        b ^= 1;
    }
    COMPUTE(b);

    // epilogue: C/D layout col = lane&15, row = (lane>>4)*4 + reg
#pragma unroll
    for (int mi = 0; mi < 4; ++mi) {
#pragma unroll
        for (int ni = 0; ni < 2; ++ni) {
            const int n_g = nb + wc * 32 + ni * 16 + lr;
            const float bv = bias[n_g];
#pragma unroll
            for (int r = 0; r < 4; ++r) {
                const int m_g = mb + wr * 64 + mi * 16 + lk * 4 + r;
                float v = acc[mi][ni][r] + bv;
                if (RELU) v = fmaxf(v, 0.f);
                if (HASRES) {
                    if (RESF16)
                        v += (float)((const _Float16*)res)[(size_t)m_g * ldr + n_g];
                    else
                        v += bf2f(((const u16*)res)[(size_t)m_g * ldr + n_g]);
                }
                if (MODE == 2) outH[(size_t)m_g * 768 + n_g] = (_Float16)v;
                else           outB[(size_t)m_g * ldo + n_g] = f2bf(v);
            }
        }
    }
}

// launch 2: down0 (h1 = relu(x@Wd0.T+bd0), 96 tiles) + rest-of-cvt
__global__ __launch_bounds__(256, 2) void gemm_d0_cvt(
    const u16* __restrict__ xb, const u16* __restrict__ Wd0b,
    const float* __restrict__ bd0, u16* __restrict__ h1, CvtTab tabB)
{
    __shared__ __align__(16) char lds[49152];
    const int bid = blockIdx.x;
    if (bid < 96) {
        gemm128_body<1, 0, 0, 0>(lds, xb, 768, Wd0b, 768, bd0, h1, 384,
                                 nullptr, 0, nullptr, 12,
                                 (bid & 15) * 128, (bid >> 4) * 64);
    } else {
        do_cvt(tabB, bid - 96, threadIdx.x);
    }
}

// ---------------------------------------------------------------------------
// small per-16-row layer: weights direct from global (L2-resident)
// ---------------------------------------------------------------------------
template<int K, int NPAD, int NREAL, int RES, int OUTG>
__device__ __forceinline__ void layer16(
    const u16* __restrict__ W, int ldw, const float* __restrict__ bias,
    const u16* actIn, int ldin,
    u16* actOut, int ldout,
    const u16* resid, int ldres,
    u16* __restrict__ gout, int ldg)
{
    constexpr int TPW = NPAD / 64;
    const int tid = threadIdx.x;
    const int wave = tid >> 6, lane = tid & 63;
    const int lr = lane & 15, lk = lane >> 4;

    f32x4 acc[TPW];
#pragma unroll
    for (int t = 0; t < TPW; ++t)
#pragma unroll
        for (int e = 0; e < 4; ++e) acc[t][e] = 0.f;

#pragma unroll
    for (int kk = 0; kk < K / 32; ++kk) {
        const bf16x8 a = *(const bf16x8*)&actIn[lr * ldin + kk * 32 + lk * 8];
#pragma unroll
        for (int t = 0; t < TPW; ++t) {
            const int nc = (wave * TPW + t) * 16 + lr;
            const bf16x8 b = *(const bf16x8*)&W[(size_t)nc * ldw + kk * 32 + lk * 8];
            acc[t] = __builtin_amdgcn_mfma_f32_16x16x32_bf16(a, b, acc[t], 0, 0, 0);
        }
    }
#pragma unroll
    for (int t = 0; t < TPW; ++t) {
        const int nc = (wave * TPW + t) * 16 + lr;
        const float bv = (nc < NREAL) ? bias[nc] : 0.f;
#pragma unroll
        for (int r = 0; r < 4; ++r) {
            const int row = lk * 4 + r;
            float v = fmaxf(acc[t][r] + bv, 0.f);
            if (RES) v += bf2f(resid[row * ldres + nc]);
            const u16 o = f2bf(v);
            if (OUTG) gout[(size_t)row * ldg + nc] = o;
            else      actOut[row * ldout + nc] = o;
        }
    }
}

// ---------------------------------------------------------------------------
// launch 3: adapter GEMM (bid<192: featH = f16(x@aW.T + ab + x)) runs
// CONCURRENTLY with the fused chain d1..u2 (bid>=192, 128 blocks) — the
// adapter fills CUs the 128-block chain leaves idle.
// ---------------------------------------------------------------------------
__global__ __launch_bounds__(256, 2) void chain_ad(
    const u16* __restrict__ xb,
    const u16* __restrict__ aWb, const float* __restrict__ ab,
    _Float16* __restrict__ featH,
    const u16* __restrict__ h1,
    const u16* __restrict__ Wd1b, const float* __restrict__ bd1,
    const u16* __restrict__ Wd2b, const float* __restrict__ bd2,
    const u16* __restrict__ Wd3b, const float* __restrict__ bd3,
    const u16* __restrict__ Wu0b, const float* __restrict__ bu0,
    const u16* __restrict__ Wu1b, const float* __restrict__ bu1,
    const u16* __restrict__ Wu2b, const float* __restrict__ bu2,
    u16* __restrict__ u2)
{
    __shared__ __align__(16) char smem[49152];
    const int bid = blockIdx.x;
    const int tid = threadIdx.x;

    if (bid < 192) {
        // adapter: no relu, residual xb (bf16), f16 out
        gemm128_body<0, 1, 0, 2>(smem, xb, 768, aWb, 768, ab, nullptr, 0,
                                 xb, 768, featH, 12,
                                 (bid & 15) * 128, (bid >> 4) * 64);
        return;
    }
    // chain: 16 rows per block
    u16* As = (u16*)smem;               // 16x392 = 12544 B
    u16* Bs = (u16*)(smem + 12544);     // 16x200
    u16* Cs = (u16*)(smem + 18944);     // 16x136
    u16* Ds = (u16*)(smem + 23296);     // 16x72
    const int rb = (bid - 192) * 16;

    for (int i = tid; i < 768; i += 256) {
        const int r = i / 48, c = i - r * 48;
        *(bf16x8*)&As[r * 392 + c * 8] =
            *(const bf16x8*)&h1[(size_t)(rb + r) * 384 + c * 8];
    }
    __syncthreads();
    layer16<384, 192, 192, 0, 0>(Wd1b, 384, bd1, As, 392, Bs, 200, nullptr, 0, nullptr, 0);
    __syncthreads();
    layer16<192, 128,  96, 0, 0>(Wd2b, 192, bd2, Bs, 200, Cs, 136, nullptr, 0, nullptr, 0);
    __syncthreads();
    layer16<128,  64,  48, 0, 0>(Wd3b, 128, bd3, Cs, 136, Ds,  72, nullptr, 0, nullptr, 0);
    __syncthreads();
    u16* E = As;                 // 16 x 136
    u16* F = As + 16 * 136;      // 16 x 200
    layer16< 64, 128,  96, 1, 0>(Wu0b,  64, bu0, Ds,  72, E, 136, Cs, 136, nullptr, 0);
    __syncthreads();
    layer16<128, 192, 192, 1, 0>(Wu1b, 128, bu1, E, 136, F, 200, Bs, 200, nullptr, 0);
    __syncthreads();
    layer16<192, 384, 384, 0, 1>(Wu2b, 192, bu2, F, 200, nullptr, 0, nullptr, 0,
                                 u2 + (size_t)rb * 384, 384);
}

// launch 4: featH += relu(u2@Wu3.T + bu3)   (6 K-steps only)
__global__ __launch_bounds__(256, 2) void gemm_u3add(
    const u16* __restrict__ u2, const u16* __restrict__ Wu3b,
    const float* __restrict__ bu3, _Float16* __restrict__ featH)
{
    __shared__ __align__(16) char lds[49152];
    gemm128_body<1, 1, 1, 2>(lds, u2, 384, Wu3b, 384, bu3, nullptr, 0,
                             featH, 768, featH, 6,
                             blockIdx.x * 128, blockIdx.y * 64);
}

// ---------------------------------------------------------------------------
// L1 head: part[row][z][p] = sum_{d in 96-chunk z} -|feat[row][d]-protos[p][d]|
// Grid (16 rb, 4 pb, 8 z) = 512 blocks (2/CU). Block: 128 rows x 64 p x 96 d.
// Thread: 8 rows x 4 protos; packed-f16 sub + abs + v_dot2_f32_f16, f32 acc.
// Non-atomic coalesced float4 stores (atomics were the R4 bottleneck).
// ---------------------------------------------------------------------------
__global__ __launch_bounds__(256) void l1_kernel(
    const _Float16* __restrict__ feat, const _Float16* __restrict__ protos,
    float* __restrict__ part)
{
    __shared__ _Float16 fs[128][96];   // 24576 B
    __shared__ hf2 pt[48][64];         // 12288 B  [d-pair][proto]
    const int tid = threadIdx.x;
    const int tp = tid & 15, tr = tid >> 4;
    const int rb = blockIdx.x * 128;
    const int pb = blockIdx.y * 64;
    const int db = blockIdx.z * 96;

    // stage fs: 128x96 f16 = 1536 granules, 6/thread (coalesced b128)
    for (int i = tid; i < 1536; i += 256) {
        const int r = i / 12, c = i - r * 12;
        *(hf8*)&fs[r][c * 8] =
            *(const hf8*)&feat[(size_t)(rb + r) * 768 + db + c * 8];
    }
    // stage pt transposed pairs: thread = proto sp, 24 d (3 x hf8)
    {
        const int sp = tid & 63, q = tid >> 6;   // q = 0..3
#pragma unroll
        for (int t = 0; t < 3; ++t) {
            const hf8 v = *(const hf8*)&protos[(size_t)(pb + sp) * 768 + db + q * 24 + t * 8];
            const hf2x4 w = __builtin_bit_cast(hf2x4, v);
            const int p0 = q * 12 + t * 4;
#pragma unroll
            for (int e = 0; e < 4; ++e)
                pt[p0 + e][sp] = w.v[e];
        }
    }
    __syncthreads();

    float acc[8][4];
#pragma unroll
    for (int i = 0; i < 8; ++i)
#pragma unroll
        for (int j = 0; j < 4; ++j) acc[i][j] = 0.f;

    const hf2 one2 = {(_Float16)1.0f, (_Float16)1.0f};
#pragma unroll 2
    for (int g = 0; g < 12; ++g) {
        hf2x4 F2[8];
#pragma unroll
        for (int i = 0; i < 8; ++i)
            F2[i] = __builtin_bit_cast(hf2x4, *(const hf8*)&fs[tr + 16 * i][g * 8]);
        hf2x4 P2[4];
#pragma unroll
        for (int q = 0; q < 4; ++q)
            P2[q] = __builtin_bit_cast(hf2x4, *(const hf8*)&pt[g * 4 + q][tp * 4]);
#pragma unroll
        for (int q = 0; q < 4; ++q) {
#pragma unroll
            for (int j = 0; j < 4; ++j) {
                const hf2 pj = P2[q].v[j];
#pragma unroll
                for (int i = 0; i < 8; ++i) {
                    hf2 d = F2[i].v[q] - pj;
                    unsigned ud = __builtin_bit_cast(unsigned, d) & 0x7FFF7FFFu;
                    acc[i][j] = FDOT2(__builtin_bit_cast(hf2, ud), one2, acc[i][j]);
                }
            }
        }
    }
    const int p = pb + tp * 4;
    if (p < 200) {
#pragma unroll
        for (int i = 0; i < 8; ++i) {
            float4 v = {-acc[i][0], -acc[i][1], -acc[i][2], -acc[i][3]};
            *(float4*)&part[((size_t)(rb + tr + 16 * i) * 8 + blockIdx.z) * 200 + p] = v;
        }
    }
}

// out[row][p] = sum_z part[row][z][p]; one block per row (6.4KB contiguous)
__global__ __launch_bounds__(256) void l1_reduce(
    const float* __restrict__ part, float* __restrict__ out)
{
    const int row = blockIdx.x;
    const int p = threadIdx.x;
    if (p < 200) {
        float s = 0.f;
#pragma unroll
        for (int z = 0; z < 8; ++z)
            s += part[((size_t)row * 8 + z) * 200 + p];
        out[(size_t)row * 200 + p] = s;
    }
}

// ---------------------------------------------------------------------------
// Workspace layout (bytes). PART (13.1 MB) aliases GEMM-era scratch (dead by
// the time l1 runs). featH/proH live above.
// ---------------------------------------------------------------------------
static constexpr size_t OFF_PART  = 0;          // 2048 x 8 x 200 f32 partials
static constexpr size_t OFF_XB    = 0;          // 2048x768 bf16
static constexpr size_t OFF_AWB   = 3145728;
static constexpr size_t OFF_WD0   = 4325376;
static constexpr size_t OFF_WD1   = 4915200;
static constexpr size_t OFF_WD2   = 5062656;
static constexpr size_t OFF_WD3   = 5111808;
static constexpr size_t OFF_WU0   = 5128192;
static constexpr size_t OFF_WU1   = 5144576;
static constexpr size_t OFF_WU2   = 5193728;
static constexpr size_t OFF_WU3   = 5341184;
static constexpr size_t OFF_H1    = 5931008;    // 2048x384 bf16
static constexpr size_t OFF_U2    = 10387456;   // 2048x384 bf16
static constexpr size_t OFF_FEATH = 19660800;   // 2048x768 f16
static constexpr size_t OFF_PROH  = 22806528;   // 256x768 f16

extern "C" void kernel_launch(void* const* d_in, const int* in_sizes, int n_in,
                              void* d_out, int out_size, void* d_ws, size_t ws_size,
                              hipStream_t stream) {
    const float* x      = (const float*)d_in[0];
    const float* aW     = (const float*)d_in[1];
    const float* ab     = (const float*)d_in[2];
    const float* protos = (const float*)d_in[3];
    const float* Wd[4]  = {(const float*)d_in[4], (const float*)d_in[6],
                           (const float*)d_in[8], (const float*)d_in[10]};
    const float* bd[4]  = {(const float*)d_in[5], (const float*)d_in[7],
                           (const float*)d_in[9], (const float*)d_in[11]};
    const float* Wu[4]  = {(const float*)d_in[12], (const float*)d_in[14],
                           (const float*)d_in[16], (const float*)d_in[18]};
    const float* bu[4]  = {(const float*)d_in[13], (const float*)d_in[15],
                           (const float*)d_in[17], (const float*)d_in[19]};
    float* out = (float*)d_out;
    char* ws = (char*)d_ws;

    u16* xb    = (u16*)(ws + OFF_XB);
    u16* aWb   = (u16*)(ws + OFF_AWB);
    u16* Wd0b  = (u16*)(ws + OFF_WD0);
    u16* Wd1b  = (u16*)(ws + OFF_WD1);
    u16* Wd2b  = (u16*)(ws + OFF_WD2);
    u16* Wd3b  = (u16*)(ws + OFF_WD3);
    u16* Wu0b  = (u16*)(ws + OFF_WU0);
    u16* Wu1b  = (u16*)(ws + OFF_WU1);
    u16* Wu2b  = (u16*)(ws + OFF_WU2);
    u16* Wu3b  = (u16*)(ws + OFF_WU3);
    u16* h1    = (u16*)(ws + OFF_H1);
    u16* u2    = (u16*)(ws + OFF_U2);
    float* part = (float*)(ws + OFF_PART);
    _Float16* featH = (_Float16*)(ws + OFF_FEATH);
    _Float16* proH  = (_Float16*)(ws + OFF_PROH);

    const int SENT = 0x7FFFFFFF;

    // --- launch 1: cvt of down0 deps only (x, Wd0) ---
    CvtTab tabA;
    int blkA = 0;
    tabA.t[0] = {x,     xb,   2048, 768, 2048, 768, 0, 0};
    blkA += 2048 * 768 / 256;
    tabA.t[1] = {Wd[0], Wd0b, 384,  768, 384,  768, blkA, 0};
    blkA += 384 * 768 / 256;
    for (int j = 2; j < 11; ++j) tabA.t[j].blk0 = SENT;
    cvt_k<<<blkA, 256, 0, stream>>>(tabA);

    // --- launch 2: down0 (96 tiles) + cvt of everything else ---
    CvtTab tabB;
    int blkB = 0;
    auto setB = [&](int i, const float* s, u16* d, int N, int K, int Np, int Kp,
                    int fmt) {
        tabB.t[i] = {s, d, N, K, Np, Kp, blkB, fmt};
        blkB += (Np * Kp + 255) / 256;
    };
    setB(0, aW,     aWb,        768, 768, 768, 768, 0);
    setB(1, Wd[1],  Wd1b,       192, 384, 192, 384, 0);
    setB(2, Wd[2],  Wd2b,       96,  192, 128, 192, 0);
    setB(3, Wd[3],  Wd3b,       48,  96,  64,  128, 0);
    setB(4, Wu[0],  Wu0b,       96,  48,  128, 64,  0);
    setB(5, Wu[1],  Wu1b,       192, 96,  192, 128, 0);
    setB(6, Wu[2],  Wu2b,       384, 192, 384, 192, 0);
    setB(7, Wu[3],  Wu3b,       768, 384, 768, 384, 0);
    setB(8, protos, (u16*)proH, 200, 768, 256, 768, 1);
    for (int j = 9; j < 11; ++j) tabB.t[j].blk0 = SENT;
    gemm_d0_cvt<<<96 + blkB, 256, 0, stream>>>(xb, Wd0b, bd[0], h1, tabB);

    // --- launch 3: adapter (192 blocks) || chain d1..u2 (128 blocks) ---
    chain_ad<<<320, 256, 0, stream>>>(xb, aWb, ab, featH, h1,
        Wd1b, bd[1], Wd2b, bd[2], Wd3b, bd[3],
        Wu0b, bu[0], Wu1b, bu[1], Wu2b, bu[2], u2);

    // --- launch 4: featH += relu(u2@Wu3.T + bu3)  (6 K-steps) ---
    gemm_u3add<<<dim3(16, 12), 256, 0, stream>>>(u2, Wu3b, bu[3], featH);

    // --- launch 5+6: L1 head partials (z=8), then reduce ---
    l1_kernel<<<dim3(16, 4, 8), 256, 0, stream>>>(featH, proH, part);
    l1_reduce<<<dim3(2048), 256, 0, stream>>>(part, out);
}

// Round 13
// 78.424 us; speedup vs baseline: 9.9555x; 1.0083x over previous
//
#include <hip/hip_runtime.h>

typedef __attribute__((ext_vector_type(8))) __bf16 bf16x8;
typedef __attribute__((ext_vector_type(4))) float f32x4;
typedef _Float16 hf2 __attribute__((ext_vector_type(2)));
typedef _Float16 hf8 __attribute__((ext_vector_type(8)));
typedef unsigned short u16;
typedef struct { hf2 v[4]; } hf2x4;   // register-friendly view of hf8

__device__ __forceinline__ float bf2f(u16 h) {
    return __uint_as_float(((unsigned int)h) << 16);
}
__device__ __forceinline__ u16 f2bf(float f) {
    unsigned int u = __float_as_uint(f);
    u += 0x7fffu + ((u >> 16) & 1u);   // RNE
    return (u16)(u >> 16);
}

#if __has_builtin(__builtin_amdgcn_fdot2)
__device__ __forceinline__ float FDOT2(hf2 a, hf2 b, float c) {
    return __builtin_amdgcn_fdot2(a, b, c, false);
}
#else
__device__ __forceinline__ float FDOT2(hf2 a, hf2 b, float c) {
    return c + (float)a[0] + (float)a[1];   // b is all-ones in our use
}
#endif

#define GLOAD_LDS16(gsrc, ldst)                                                          \
    __builtin_amdgcn_global_load_lds(                                                    \
        (__attribute__((address_space(1))) unsigned int*)(gsrc),                         \
        (__attribute__((address_space(3))) unsigned int*)(ldst), 16, 0, 0)

// ---------------------------------------------------------------------------
// f32 -> bf16/f16 convert with zero-padding. Unused tab entries: blk0=INT_MAX.
// ---------------------------------------------------------------------------
struct CvtDesc { const float* src; u16* dst; int N, K, Npad, Kpad, blk0, fmt; };
struct CvtTab { CvtDesc t[11]; };

__device__ __forceinline__ void do_cvt(const CvtTab& tab, int vb, int tid) {
    int ti = 0;
#pragma unroll
    for (int j = 1; j < 11; ++j)
        if (vb >= tab.t[j].blk0) ti = j;
    const CvtDesc c = tab.t[ti];
    long i = (long)(vb - c.blk0) * 256 + tid;
    long tot = (long)c.Npad * c.Kpad;
    if (i >= tot) return;
    int n = (int)(i / c.Kpad);
    int k = (int)(i - (long)n * c.Kpad);
    float v = (n < c.N && k < c.K) ? c.src[(long)n * c.K + k] : 0.f;
    c.dst[i] = c.fmt ? __builtin_bit_cast(u16, (_Float16)v) : f2bf(v);
}

__global__ __launch_bounds__(256) void cvt_k(CvtTab tab) {
    do_cvt(tab, blockIdx.x, threadIdx.x);
}

// ---------------------------------------------------------------------------
// 128x64-tile double-buffered bf16 MFMA GEMM (2-phase pipeline): STAGE(next)
// issued BEFORE COMPUTE(cur); one vmcnt-drain barrier per K-step.
// 256 thr = 4 waves as 2x2 over (128,64); wave tile 64x32 = acc[4][2].
// XOR-swizzled granules via pre-swizzled global source + linear LDS dest.
// ---------------------------------------------------------------------------
template<int RELU, int HASRES, int RESF16, int MODE>
__device__ __forceinline__ void gemm128_body(
    char* lds,
    const u16* __restrict__ A, int lda,
    const u16* __restrict__ W, int ldw,
    const float* __restrict__ bias,
    u16* __restrict__ outB, int ldo,
    const void* __restrict__ res, int ldr,
    _Float16* __restrict__ outH,
    int nk, int mb, int nb)
{
    const int tid = threadIdx.x;
    const int wave = tid >> 6, lane = tid & 63;
    const int lr = lane & 15, lk = lane >> 4;
    const int wr = wave >> 1, wc = wave & 1;

    f32x4 acc[4][2];
#pragma unroll
    for (int i = 0; i < 4; ++i)
#pragma unroll
        for (int j = 0; j < 2; ++j)
#pragma unroll
            for (int e = 0; e < 4; ++e) acc[i][j][e] = 0.f;

    int ra[4], la[4], rb_[2], lb[2];
#pragma unroll
    for (int t = 0; t < 4; ++t) {
        int g = t * 256 + tid;
        ra[t] = g >> 3; la[t] = (g & 7) ^ (ra[t] & 7);
    }
#pragma unroll
    for (int t = 0; t < 2; ++t) {
        int g = t * 256 + tid;
        rb_[t] = g >> 3; lb[t] = (g & 7) ^ (rb_[t] & 7);
    }

    auto STAGE = [&](int b, int kt) {
        const int kk = kt * 64;
        char* dA = lds + b * 24576;
        char* dB = dA + 16384;
#pragma unroll
        for (int t = 0; t < 4; ++t)
            GLOAD_LDS16(A + (size_t)(mb + ra[t]) * lda + kk + la[t] * 8,
                        dA + t * 4096 + wave * 1024);
#pragma unroll
        for (int t = 0; t < 2; ++t)
            GLOAD_LDS16(W + (size_t)(nb + rb_[t]) * ldw + kk + lb[t] * 8,
                        dB + t * 4096 + wave * 1024);
    };
    auto COMPUTE = [&](int b) {
        char* sA = lds + b * 24576;
        char* sB = sA + 16384;
#pragma unroll
        for (int ks = 0; ks < 2; ++ks) {
            bf16x8 af[4], bfr[2];
#pragma unroll
            for (int mi = 0; mi < 4; ++mi) {
                int m_loc = wr * 64 + mi * 16 + lr;
                int gr = (ks * 4 + lk) ^ (m_loc & 7);
                af[mi] = *(const bf16x8*)(sA + m_loc * 128 + gr * 16);
            }
#pragma unroll
            for (int ni = 0; ni < 2; ++ni) {
                int n_loc = wc * 32 + ni * 16 + lr;
                int gr = (ks * 4 + lk) ^ (n_loc & 7);
                bfr[ni] = *(const bf16x8*)(sB + n_loc * 128 + gr * 16);
            }
#pragma unroll
            for (int mi = 0; mi < 4; ++mi)
#pragma unroll
                for (int ni = 0; ni < 2; ++ni)
                    acc[mi][ni] = __builtin_amdgcn_mfma_f32_16x16x32_bf16(
                        af[mi], bfr[ni], acc[mi][ni], 0, 0, 0);
        }
    };

    STAGE(0, 0);
    __syncthreads();
    int b = 0;
    for (int kt = 0; kt < nk - 1; ++kt) {
        STAGE(b ^ 1, kt + 1);
        COMPUTE(b);
        __syncthreads();
        b ^= 1;
    }
    COMPUTE(b);

    // epilogue: C/D layout col = lane&15, row = (lane>>4)*4 + reg
#pragma unroll
    for (int mi = 0; mi < 4; ++mi) {
#pragma unroll
        for (int ni = 0; ni < 2; ++ni) {
            const int n_g = nb + wc * 32 + ni * 16 + lr;
            const float bv = bias[n_g];
#pragma unroll
            for (int r = 0; r < 4; ++r) {
                const int m_g = mb + wr * 64 + mi * 16 + lk * 4 + r;
                float v = acc[mi][ni][r] + bv;
                if (RELU) v = fmaxf(v, 0.f);
                if (HASRES) {
                    if (RESF16)
                        v += (float)((const _Float16*)res)[(size_t)m_g * ldr + n_g];
                    else
                        v += bf2f(((const u16*)res)[(size_t)m_g * ldr + n_g]);
                }
                if (MODE == 2) outH[(size_t)m_g * 768 + n_g] = (_Float16)v;
                else           outB[(size_t)m_g * ldo + n_g] = f2bf(v);
            }
        }
    }
}

// launch 2: down0 (96 tiles) + adapter (192 tiles: featH = f16(x@aW.T+ab+x))
//           + cvt of remaining weights/protos — all depend only on launch 1.
__global__ __launch_bounds__(256, 2) void gemm_d0ad_cvt(
    const u16* __restrict__ xb, const u16* __restrict__ Wd0b,
    const float* __restrict__ bd0, u16* __restrict__ h1,
    const u16* __restrict__ aWb, const float* __restrict__ ab,
    _Float16* __restrict__ featH, CvtTab tabB)
{
    __shared__ __align__(16) char lds[49152];
    const int bid = blockIdx.x;
    if (bid < 96) {
        gemm128_body<1, 0, 0, 0>(lds, xb, 768, Wd0b, 768, bd0, h1, 384,
                                 nullptr, 0, nullptr, 12,
                                 (bid & 15) * 128, (bid >> 4) * 64);
    } else if (bid < 288) {
        const int b2 = bid - 96;
        gemm128_body<0, 1, 0, 2>(lds, xb, 768, aWb, 768, ab, nullptr, 0,
                                 xb, 768, featH, 12,
                                 (b2 & 15) * 128, (b2 >> 4) * 64);
    } else {
        do_cvt(tabB, bid - 288, threadIdx.x);
    }
}

// ---------------------------------------------------------------------------
// chain512: d1..u2, 128 blocks x 512 thr (8 waves = 4 N-waves x 2 K-waves).
// Each layer splits its K-loop across the 2 K-wave groups (halves the serial
// latency chain); kw=1 writes f32 partials to LDS, kw=0 combines + epilogue.
// Weights direct from global (L2-resident). Two barriers per layer.
// comb: 24 N-tiles x 64 lanes x 4 f32 = 6144 floats = 24576 B
// (R12 BUG: was declared 1536 floats -> 18KB LDS OOB -> corruption).
// ---------------------------------------------------------------------------
template<int K, int NPAD, int NREAL, int RES, int OUTG>
__device__ __forceinline__ void layer16s(
    const u16* __restrict__ W, int ldw, const float* __restrict__ bias,
    const u16* actIn, int ldin,
    u16* actOut, int ldout,
    const u16* resid, int ldres,
    u16* __restrict__ gout, int ldg,
    float* comb)
{
    constexpr int TPW = NPAD / 64;     // 16-wide N-tiles per N-wave
    constexpr int KK = K / 32;         // total K-steps (even for all layers)
    constexpr int KH = KK / 2;         // per K-wave
    const int tid = threadIdx.x;
    const int w = tid >> 6, lane = tid & 63;
    const int nw = w & 3, kw = w >> 2;
    const int lr = lane & 15, lk = lane >> 4;

    f32x4 acc[TPW];
#pragma unroll
    for (int t = 0; t < TPW; ++t)
#pragma unroll
        for (int e = 0; e < 4; ++e) acc[t][e] = 0.f;

#pragma unroll
    for (int s = 0; s < KH; ++s) {
        const int kk = kw * KH + s;
        const bf16x8 a = *(const bf16x8*)&actIn[lr * ldin + kk * 32 + lk * 8];
#pragma unroll
        for (int t = 0; t < TPW; ++t) {
            const int nc = (nw * TPW + t) * 16 + lr;
            const bf16x8 b = *(const bf16x8*)&W[(size_t)nc * ldw + kk * 32 + lk * 8];
            acc[t] = __builtin_amdgcn_mfma_f32_16x16x32_bf16(a, b, acc[t], 0, 0, 0);
        }
    }
    if (kw == 1) {
#pragma unroll
        for (int t = 0; t < TPW; ++t)
            *(f32x4*)(comb + ((size_t)(nw * TPW + t) * 64 + lane) * 4) = acc[t];
    }
    __syncthreads();
    if (kw == 0) {
#pragma unroll
        for (int t = 0; t < TPW; ++t) {
            const f32x4 o = *(const f32x4*)(comb + ((size_t)(nw * TPW + t) * 64 + lane) * 4);
            const int nc = (nw * TPW + t) * 16 + lr;
            const float bv = (nc < NREAL) ? bias[nc] : 0.f;
#pragma unroll
            for (int r = 0; r < 4; ++r) {
                const int row = lk * 4 + r;
                float v = fmaxf(acc[t][r] + o[r] + bv, 0.f);
                if (RES) v += bf2f(resid[row * ldres + nc]);
                const u16 ov = f2bf(v);
                if (OUTG) gout[(size_t)row * ldg + nc] = ov;
                else      actOut[row * ldout + nc] = ov;
            }
        }
    }
    __syncthreads();
}

__global__ __launch_bounds__(512) void chain512(
    const u16* __restrict__ h1,
    const u16* __restrict__ Wd1b, const float* __restrict__ bd1,
    const u16* __restrict__ Wd2b, const float* __restrict__ bd2,
    const u16* __restrict__ Wd3b, const float* __restrict__ bd3,
    const u16* __restrict__ Wu0b, const float* __restrict__ bu0,
    const u16* __restrict__ Wu1b, const float* __restrict__ bu1,
    const u16* __restrict__ Wu2b, const float* __restrict__ bu2,
    u16* __restrict__ u2)
{
    __shared__ u16 As[16 * 392];      // h1 in; later E (16x136), F (16x200)
    __shared__ u16 Bs[16 * 200];      // h2 skip
    __shared__ u16 Cs[16 * 136];      // h3 skip
    __shared__ u16 Ds[16 * 72];       // h4
    __shared__ float comb[6144];      // 24 tiles x 64 lanes x f32x4 = 24576 B
    const int tid = threadIdx.x;
    const int rb = blockIdx.x * 16;

    for (int i = tid; i < 768; i += 512) {
        const int r = i / 48, c = i - r * 48;
        *(bf16x8*)&As[r * 392 + c * 8] =
            *(const bf16x8*)&h1[(size_t)(rb + r) * 384 + c * 8];
    }
    __syncthreads();
    layer16s<384, 192, 192, 0, 0>(Wd1b, 384, bd1, As, 392, Bs, 200, nullptr, 0, nullptr, 0, comb);
    layer16s<192, 128,  96, 0, 0>(Wd2b, 192, bd2, Bs, 200, Cs, 136, nullptr, 0, nullptr, 0, comb);
    layer16s<128,  64,  48, 0, 0>(Wd3b, 128, bd3, Cs, 136, Ds,  72, nullptr, 0, nullptr, 0, comb);
    u16* E = As;                 // 16 x 136
    u16* F = As + 16 * 136;      // 16 x 200
    layer16s< 64, 128,  96, 1, 0>(Wu0b,  64, bu0, Ds,  72, E, 136, Cs, 136, nullptr, 0, comb);
    layer16s<128, 192, 192, 1, 0>(Wu1b, 128, bu1, E, 136, F, 200, Bs, 200, nullptr, 0, comb);
    layer16s<192, 384, 384, 0, 1>(Wu2b, 192, bu2, F, 200, nullptr, 0, nullptr, 0,
                                  u2 + (size_t)rb * 384, 384, comb);
}

// launch 4: featH += relu(u2@Wu3.T + bu3)   (6 K-steps)
__global__ __launch_bounds__(256, 2) void gemm_u3add(
    const u16* __restrict__ u2, const u16* __restrict__ Wu3b,
    const float* __restrict__ bu3, _Float16* __restrict__ featH)
{
    __shared__ __align__(16) char lds[49152];
    gemm128_body<1, 1, 1, 2>(lds, u2, 384, Wu3b, 384, bu3, nullptr, 0,
                             featH, 768, featH, 6,
                             blockIdx.x * 128, blockIdx.y * 64);
}

// ---------------------------------------------------------------------------
// L1 head: part[row][z][p] = sum_{d in 96-chunk z} -|feat[row][d]-protos[p][d]|
// Grid (16 rb, 4 pb, 8 z) = 512 blocks (2/CU). Block: 128 rows x 64 p x 96 d.
// Thread: 8 rows x 4 protos; packed-f16 sub + abs + v_dot2_f32_f16, f32 acc.
// Non-atomic coalesced float4 stores; separate reduce launch (proven path).
// ---------------------------------------------------------------------------
__global__ __launch_bounds__(256) void l1_kernel(
    const _Float16* __restrict__ feat, const _Float16* __restrict__ protos,
    float* __restrict__ part)
{
    __shared__ _Float16 fs[128][96];   // 24576 B
    __shared__ hf2 pt[48][64];         // 12288 B  [d-pair][proto]
    const int tid = threadIdx.x;
    const int tp = tid & 15, tr = tid >> 4;
    const int rb = blockIdx.x * 128;
    const int pb = blockIdx.y * 64;
    const int db = blockIdx.z * 96;

    // stage fs: 128x96 f16 = 1536 granules, 6/thread (coalesced b128)
    for (int i = tid; i < 1536; i += 256) {
        const int r = i / 12, c = i - r * 12;
        *(hf8*)&fs[r][c * 8] =
            *(const hf8*)&feat[(size_t)(rb + r) * 768 + db + c * 8];
    }
    // stage pt transposed pairs: thread = proto sp, 24 d (3 x hf8)
    {
        const int sp = tid & 63, q = tid >> 6;   // q = 0..3
#pragma unroll
        for (int t = 0; t < 3; ++t) {
            const hf8 v = *(const hf8*)&protos[(size_t)(pb + sp) * 768 + db + q * 24 + t * 8];
            const hf2x4 w = __builtin_bit_cast(hf2x4, v);
            const int p0 = q * 12 + t * 4;
#pragma unroll
            for (int e = 0; e < 4; ++e)
                pt[p0 + e][sp] = w.v[e];
        }
    }
    __syncthreads();

    float acc[8][4];
#pragma unroll
    for (int i = 0; i < 8; ++i)
#pragma unroll
        for (int j = 0; j < 4; ++j) acc[i][j] = 0.f;

    const hf2 one2 = {(_Float16)1.0f, (_Float16)1.0f};
#pragma unroll 2
    for (int g = 0; g < 12; ++g) {
        hf2x4 F2[8];
#pragma unroll
        for (int i = 0; i < 8; ++i)
            F2[i] = __builtin_bit_cast(hf2x4, *(const hf8*)&fs[tr + 16 * i][g * 8]);
        hf2x4 P2[4];
#pragma unroll
        for (int q = 0; q < 4; ++q)
            P2[q] = __builtin_bit_cast(hf2x4, *(const hf8*)&pt[g * 4 + q][tp * 4]);
#pragma unroll
        for (int q = 0; q < 4; ++q) {
#pragma unroll
            for (int j = 0; j < 4; ++j) {
                const hf2 pj = P2[q].v[j];
#pragma unroll
                for (int i = 0; i < 8; ++i) {
                    hf2 d = F2[i].v[q] - pj;
                    unsigned ud = __builtin_bit_cast(unsigned, d) & 0x7FFF7FFFu;
                    acc[i][j] = FDOT2(__builtin_bit_cast(hf2, ud), one2, acc[i][j]);
                }
            }
        }
    }
    const int p = pb + tp * 4;
    if (p < 200) {
#pragma unroll
        for (int i = 0; i < 8; ++i) {
            float4 v = {-acc[i][0], -acc[i][1], -acc[i][2], -acc[i][3]};
            *(float4*)&part[((size_t)(rb + tr + 16 * i) * 8 + blockIdx.z) * 200 + p] = v;
        }
    }
}

// out[row][p] = sum_z part[row][z][p]; one block per row (6.4KB contiguous)
__global__ __launch_bounds__(256) void l1_reduce(
    const float* __restrict__ part, float* __restrict__ out)
{
    const int row = blockIdx.x;
    const int p = threadIdx.x;
    if (p < 200) {
        float s = 0.f;
#pragma unroll
        for (int z = 0; z < 8; ++z)
            s += part[((size_t)row * 8 + z) * 200 + p];
        out[(size_t)row * 200 + p] = s;
    }
}

// ---------------------------------------------------------------------------
// Workspace layout (bytes). PART (13.1 MB) aliases GEMM-era scratch (dead by
// the time l1 runs). featH/proH live above.
// ---------------------------------------------------------------------------
static constexpr size_t OFF_PART  = 0;          // 2048 x 8 x 200 f32 partials
static constexpr size_t OFF_XB    = 0;          // 2048x768 bf16
static constexpr size_t OFF_AWB   = 3145728;
static constexpr size_t OFF_WD0   = 4325376;
static constexpr size_t OFF_WD1   = 4915200;
static constexpr size_t OFF_WD2   = 5062656;
static constexpr size_t OFF_WD3   = 5111808;
static constexpr size_t OFF_WU0   = 5128192;
static constexpr size_t OFF_WU1   = 5144576;
static constexpr size_t OFF_WU2   = 5193728;
static constexpr size_t OFF_WU3   = 5341184;
static constexpr size_t OFF_H1    = 5931008;    // 2048x384 bf16
static constexpr size_t OFF_U2    = 10387456;   // 2048x384 bf16
static constexpr size_t OFF_FEATH = 19660800;   // 2048x768 f16
static constexpr size_t OFF_PROH  = 22806528;   // 256x768 f16

extern "C" void kernel_launch(void* const* d_in, const int* in_sizes, int n_in,
                              void* d_out, int out_size, void* d_ws, size_t ws_size,
                              hipStream_t stream) {
    const float* x      = (const float*)d_in[0];
    const float* aW     = (const float*)d_in[1];
    const float* ab     = (const float*)d_in[2];
    const float* protos = (const float*)d_in[3];
    const float* Wd[4]  = {(const float*)d_in[4], (const float*)d_in[6],
                           (const float*)d_in[8], (const float*)d_in[10]};
    const float* bd[4]  = {(const float*)d_in[5], (const float*)d_in[7],
                           (const float*)d_in[9], (const float*)d_in[11]};
    const float* Wu[4]  = {(const float*)d_in[12], (const float*)d_in[14],
                           (const float*)d_in[16], (const float*)d_in[18]};
    const float* bu[4]  = {(const float*)d_in[13], (const float*)d_in[15],
                           (const float*)d_in[17], (const float*)d_in[19]};
    float* out = (float*)d_out;
    char* ws = (char*)d_ws;

    u16* xb    = (u16*)(ws + OFF_XB);
    u16* aWb   = (u16*)(ws + OFF_AWB);
    u16* Wd0b  = (u16*)(ws + OFF_WD0);
    u16* Wd1b  = (u16*)(ws + OFF_WD1);
    u16* Wd2b  = (u16*)(ws + OFF_WD2);
    u16* Wd3b  = (u16*)(ws + OFF_WD3);
    u16* Wu0b  = (u16*)(ws + OFF_WU0);
    u16* Wu1b  = (u16*)(ws + OFF_WU1);
    u16* Wu2b  = (u16*)(ws + OFF_WU2);
    u16* Wu3b  = (u16*)(ws + OFF_WU3);
    u16* h1    = (u16*)(ws + OFF_H1);
    u16* u2    = (u16*)(ws + OFF_U2);
    float* part = (float*)(ws + OFF_PART);
    _Float16* featH = (_Float16*)(ws + OFF_FEATH);
    _Float16* proH  = (_Float16*)(ws + OFF_PROH);

    const int SENT = 0x7FFFFFFF;

    // --- launch 1: cvt of launch-2 deps (x, Wd0, aW) ---
    CvtTab tabA;
    int blkA = 0;
    tabA.t[0] = {x,     xb,   2048, 768, 2048, 768, 0, 0};
    blkA += 2048 * 768 / 256;
    tabA.t[1] = {Wd[0], Wd0b, 384,  768, 384,  768, blkA, 0};
    blkA += 384 * 768 / 256;
    tabA.t[2] = {aW,    aWb,  768,  768, 768,  768, blkA, 0};
    blkA += 768 * 768 / 256;
    for (int j = 3; j < 11; ++j) tabA.t[j].blk0 = SENT;
    cvt_k<<<blkA, 256, 0, stream>>>(tabA);

    // --- launch 2: down0 (96) + adapter (192) + cvt of the rest ---
    CvtTab tabB;
    int blkB = 0;
    auto setB = [&](int i, const float* s, u16* d, int N, int K, int Np, int Kp,
                    int fmt) {
        tabB.t[i] = {s, d, N, K, Np, Kp, blkB, fmt};
        blkB += (Np * Kp + 255) / 256;
    };
    setB(0, Wd[1],  Wd1b,       192, 384, 192, 384, 0);
    setB(1, Wd[2],  Wd2b,       96,  192, 128, 192, 0);
    setB(2, Wd[3],  Wd3b,       48,  96,  64,  128, 0);
    setB(3, Wu[0],  Wu0b,       96,  48,  128, 64,  0);
    setB(4, Wu[1],  Wu1b,       192, 96,  192, 128, 0);
    setB(5, Wu[2],  Wu2b,       384, 192, 384, 192, 0);
    setB(6, Wu[3],  Wu3b,       768, 384, 768, 384, 0);
    setB(7, protos, (u16*)proH, 200, 768, 256, 768, 1);
    for (int j = 8; j < 11; ++j) tabB.t[j].blk0 = SENT;
    gemm_d0ad_cvt<<<288 + blkB, 256, 0, stream>>>(xb, Wd0b, bd[0], h1,
                                                  aWb, ab, featH, tabB);

    // --- launch 3: chain d1..u2 (K-split, 512 thr) ---
    chain512<<<128, 512, 0, stream>>>(h1,
        Wd1b, bd[1], Wd2b, bd[2], Wd3b, bd[3],
        Wu0b, bu[0], Wu1b, bu[1], Wu2b, bu[2], u2);

    // --- launch 4: featH += relu(u2@Wu3.T + bu3) ---
    gemm_u3add<<<dim3(16, 12), 256, 0, stream>>>(u2, Wu3b, bu[3], featH);

    // --- launch 5+6: L1 head partials (z=8), then reduce ---
    l1_kernel<<<dim3(16, 4, 8), 256, 0, stream>>>(featH, proH, part);
    l1_reduce<<<dim3(2048), 256, 0, stream>>>(part, out);
}